// Round 1
// baseline (189.492 us; speedup 1.0000x reference)
//
#include <hip/hip_runtime.h>

#define B_SZ 64
#define S_SZ 2048
#define RNN 1024
#define ATT 512

// ws layout in floats:
//   att_h   : [B_SZ*ATT]          off 0          (32768)
//   scores  : [B_SZ*S_SZ]         off 32768      (131072)  (softmax in-place -> weights)
//   partials: [B_SZ*16*RNN]       off 163840     (1048576)
#define OFF_ATTH   0
#define OFF_SCORES 32768
#define OFF_PART   163840

__device__ __forceinline__ float fast_tanh(float x) {
    float t = __expf(2.0f * x);
    return 1.0f - 2.0f / (t + 1.0f);
}

// --- Kernel 0: att_h = h @ W_h^T + b_h   [B,ATT] ---
__global__ __launch_bounds__(256) void k_atth(const float* __restrict__ h,
                                              const float* __restrict__ Wh,
                                              const float* __restrict__ bh,
                                              float* __restrict__ att_h) {
    int b = blockIdx.y;
    int j = blockIdx.x * 256 + threadIdx.x;   // 0..511
    __shared__ float hs[RNN];
    const float* hrow = h + (size_t)b * RNN;
    for (int i = threadIdx.x; i < RNN; i += 256) hs[i] = hrow[i];
    __syncthreads();
    const float4* w4 = (const float4*)(Wh + (size_t)j * RNN);
    const float4* h4 = (const float4*)hs;
    float acc = bh[j];
    #pragma unroll 8
    for (int k = 0; k < RNN / 4; ++k) {
        float4 w = w4[k];
        float4 hv = h4[k];   // uniform per-wave index -> LDS broadcast, conflict-free
        acc += w.x * hv.x + w.y * hv.y + w.z * hv.z + w.w * hv.w;
    }
    att_h[(size_t)b * ATT + j] = acc;
}

// --- Kernel A: scores[b,s] = w_a . tanh(p[b,s,:] + att_h[b,:]) + b_a ---
// grid (S/4, B), block 256 = 4 waves, one wave per s
__global__ __launch_bounds__(256) void k_scores(const float* __restrict__ p,
                                                const float* __restrict__ att_h,
                                                const float* __restrict__ w_a,
                                                const float* __restrict__ b_a,
                                                float* __restrict__ scores) {
    int b = blockIdx.y;
    __shared__ float ah[ATT];
    __shared__ float wa[ATT];
    for (int i = threadIdx.x; i < ATT; i += 256) {
        ah[i] = att_h[(size_t)b * ATT + i];
        wa[i] = w_a[i];
    }
    __syncthreads();
    int wave = threadIdx.x >> 6;
    int lane = threadIdx.x & 63;
    int s = blockIdx.x * 4 + wave;

    const float4* p4  = (const float4*)(p + ((size_t)b * S_SZ + s) * ATT);
    const float4* ah4 = (const float4*)ah;
    const float4* wa4 = (const float4*)wa;

    float4 x0 = p4[lane];        // floats 4*lane .. 4*lane+3
    float4 x1 = p4[64 + lane];   // floats 256+4*lane ..
    float4 a0 = ah4[lane];
    float4 a1 = ah4[64 + lane];
    float4 w0 = wa4[lane];
    float4 w1 = wa4[64 + lane];

    float part = 0.f;
    part += w0.x * fast_tanh(x0.x + a0.x);
    part += w0.y * fast_tanh(x0.y + a0.y);
    part += w0.z * fast_tanh(x0.z + a0.z);
    part += w0.w * fast_tanh(x0.w + a0.w);
    part += w1.x * fast_tanh(x1.x + a1.x);
    part += w1.y * fast_tanh(x1.y + a1.y);
    part += w1.z * fast_tanh(x1.z + a1.z);
    part += w1.w * fast_tanh(x1.w + a1.w);

    #pragma unroll
    for (int off = 32; off > 0; off >>= 1)
        part += __shfl_xor(part, off, 64);

    if (lane == 0) scores[(size_t)b * S_SZ + s] = part + b_a[0];
}

// --- Kernel B: masked softmax per row, in-place over scores ---
// grid B, block 256; 8 scores per thread
__global__ __launch_bounds__(256) void k_softmax(float* __restrict__ scores,
                                                 const int* __restrict__ mask) {
    int b = blockIdx.x;
    int t = threadIdx.x;
    __shared__ float red[256];
    float* srow = scores + (size_t)b * S_SZ;
    const int* mrow = mask + (size_t)b * S_SZ;

    float v[8];
    int m[8];
    float mx = -1e30f;
    #pragma unroll
    for (int i = 0; i < 8; ++i) {
        int idx = t + 256 * i;
        v[i] = srow[idx];
        m[i] = mrow[idx];
        mx = fmaxf(mx, v[i]);
    }
    red[t] = mx;
    __syncthreads();
    for (int o = 128; o > 0; o >>= 1) {
        if (t < o) red[t] = fmaxf(red[t], red[t + o]);
        __syncthreads();
    }
    float M = red[0];
    __syncthreads();

    float e[8];
    float sum = 0.f;
    #pragma unroll
    for (int i = 0; i < 8; ++i) {
        e[i] = m[i] ? __expf(v[i] - M) : 0.f;
        sum += e[i];
    }
    red[t] = sum;
    __syncthreads();
    for (int o = 128; o > 0; o >>= 1) {
        if (t < o) red[t] += red[t + o];
        __syncthreads();
    }
    float inv = 1.f / red[0];
    #pragma unroll
    for (int i = 0; i < 8; ++i)
        srow[t + 256 * i] = e[i] * inv;
}

// --- Kernel C: partials[b,c,:] = sum_{s in chunk c} w[b,s] * att_feats[b,s,:] ---
// grid (16, B), block 256; each thread owns 4 consecutive d (float4)
__global__ __launch_bounds__(256) void k_wsum(const float* __restrict__ feats,
                                              const float* __restrict__ weights,
                                              float* __restrict__ partials) {
    int c = blockIdx.x;
    int b = blockIdx.y;
    int t = threadIdx.x;
    __shared__ float w[128];
    int s0 = c * 128;
    if (t < 128) w[t] = weights[(size_t)b * S_SZ + s0 + t];
    __syncthreads();

    const float4* f4 = (const float4*)(feats + ((size_t)b * S_SZ + s0) * RNN);
    float4 acc = {0.f, 0.f, 0.f, 0.f};
    #pragma unroll 4
    for (int i = 0; i < 128; ++i) {
        float4 v = f4[(size_t)i * 256 + t];
        float wi = w[i];   // broadcast
        acc.x += wi * v.x;
        acc.y += wi * v.y;
        acc.z += wi * v.z;
        acc.w += wi * v.w;
    }
    float4* out4 = (float4*)partials;
    out4[((size_t)b * 16 + c) * 256 + t] = acc;
}

// --- Kernel D: out[b,:] = sum_c partials[b,c,:] ---
__global__ __launch_bounds__(256) void k_reduce(const float* __restrict__ partials,
                                                float* __restrict__ out) {
    int b = blockIdx.x;
    int t = threadIdx.x;
    const float4* p4 = (const float4*)(partials + (size_t)b * 16 * RNN);
    float4 acc = {0.f, 0.f, 0.f, 0.f};
    #pragma unroll
    for (int c = 0; c < 16; ++c) {
        float4 v = p4[c * 256 + t];
        acc.x += v.x;
        acc.y += v.y;
        acc.z += v.z;
        acc.w += v.w;
    }
    ((float4*)out)[(size_t)b * 256 + t] = acc;
}

extern "C" void kernel_launch(void* const* d_in, const int* in_sizes, int n_in,
                              void* d_out, int out_size, void* d_ws, size_t ws_size,
                              hipStream_t stream) {
    const float* h         = (const float*)d_in[0];
    const float* att_feats = (const float*)d_in[1];
    const float* p_att     = (const float*)d_in[2];
    const int*   att_masks = (const int*)d_in[3];
    const float* W_h       = (const float*)d_in[4];
    const float* b_h       = (const float*)d_in[5];
    const float* w_a       = (const float*)d_in[6];
    const float* b_a       = (const float*)d_in[7];
    float* out = (float*)d_out;

    float* wsf = (float*)d_ws;
    float* att_h    = wsf + OFF_ATTH;
    float* scores   = wsf + OFF_SCORES;   // becomes weights in-place
    float* partials = wsf + OFF_PART;

    k_atth<<<dim3(2, B_SZ), 256, 0, stream>>>(h, W_h, b_h, att_h);
    k_scores<<<dim3(S_SZ / 4, B_SZ), 256, 0, stream>>>(p_att, att_h, w_a, b_a, scores);
    k_softmax<<<dim3(B_SZ), 256, 0, stream>>>(scores, att_masks);
    k_wsum<<<dim3(16, B_SZ), 256, 0, stream>>>(att_feats, scores, partials);
    k_reduce<<<dim3(B_SZ), 256, 0, stream>>>(partials, out);
}

// Round 2
// 189.409 us; speedup vs baseline: 1.0004x; 1.0004x over previous
//
#include <hip/hip_runtime.h>

#define B_SZ 64
#define S_SZ 2048
#define RNN 1024
#define ATT 512
#define NCHUNK 32
#define CHUNK_S (S_SZ / NCHUNK)   // 64

// ws layout in floats:
//   att_h   : [B_SZ*ATT]              off 0        (32768)
//   u       : [B_SZ*S_SZ]             off 32768    (131072)  unnormalized masked exp-scores
//   partials: [B_SZ*NCHUNK*RNN]       off 163840   (2097152)
#define OFF_ATTH   0
#define OFF_U      32768
#define OFF_PART   163840

// tanh(x) = 1 - 2/(1 + 2^(x * 2/ln2))
__device__ __forceinline__ float fast_tanh(float x) {
    float t = __builtin_exp2f(x * 2.885390082f);
    return 1.0f - 2.0f * __builtin_amdgcn_rcpf(t + 1.0f);
}

// --- Kernel 0: att_h = h @ W_h^T + b_h   [B,ATT] ---
// grid (4, B), block 128
__global__ __launch_bounds__(128) void k_atth(const float* __restrict__ h,
                                              const float* __restrict__ Wh,
                                              const float* __restrict__ bh,
                                              float* __restrict__ att_h) {
    int b = blockIdx.y;
    int j = blockIdx.x * 128 + threadIdx.x;   // 0..511
    __shared__ float hs[RNN];
    const float* hrow = h + (size_t)b * RNN;
    for (int i = threadIdx.x; i < RNN; i += 128) hs[i] = hrow[i];
    __syncthreads();
    const float4* w4 = (const float4*)(Wh + (size_t)j * RNN);
    const float4* h4 = (const float4*)hs;
    float acc = bh[j];
    #pragma unroll 8
    for (int k = 0; k < RNN / 4; ++k) {
        float4 w = w4[k];
        float4 hv = h4[k];   // wave-uniform index -> LDS broadcast
        acc += w.x * hv.x + w.y * hv.y + w.z * hv.z + w.w * hv.w;
    }
    att_h[(size_t)b * ATT + j] = acc;
}

// --- Kernel A: u[b,s] = mask[b,s] * exp(w_a . tanh(p[b,s,:] + att_h[b,:]) + b_a) ---
// grid (S/32, B), block 256 = 4 waves; each wave handles 8 consecutive s
__global__ __launch_bounds__(256, 4) void k_scores_u(const float* __restrict__ p,
                                                     const float* __restrict__ att_h,
                                                     const float* __restrict__ w_a,
                                                     const float* __restrict__ b_a,
                                                     const int* __restrict__ mask,
                                                     float* __restrict__ u) {
    int b = blockIdx.y;
    __shared__ float ah[ATT];
    __shared__ float wa[ATT];
    for (int i = threadIdx.x; i < ATT; i += 256) {
        ah[i] = att_h[(size_t)b * ATT + i];
        wa[i] = w_a[i];
    }
    __syncthreads();
    int wave = threadIdx.x >> 6;
    int lane = threadIdx.x & 63;
    float ba = b_a[0];

    // hoist per-lane fragments of att_h and w_a into registers (once per block)
    const float4* ah4 = (const float4*)ah;
    const float4* wa4 = (const float4*)wa;
    float4 a0 = ah4[lane];
    float4 a1 = ah4[64 + lane];
    float4 w0 = wa4[lane];
    float4 w1 = wa4[64 + lane];

    int s_base = blockIdx.x * 32 + wave * 8;
    const float4* p4 = (const float4*)(p + ((size_t)b * S_SZ + s_base) * ATT);

    #pragma unroll 2
    for (int i = 0; i < 8; ++i) {
        float4 x0 = p4[(size_t)i * 128 + lane];
        float4 x1 = p4[(size_t)i * 128 + 64 + lane];

        float part;
        part  = w0.x * fast_tanh(x0.x + a0.x);
        part += w0.y * fast_tanh(x0.y + a0.y);
        part += w0.z * fast_tanh(x0.z + a0.z);
        part += w0.w * fast_tanh(x0.w + a0.w);
        part += w1.x * fast_tanh(x1.x + a1.x);
        part += w1.y * fast_tanh(x1.y + a1.y);
        part += w1.z * fast_tanh(x1.z + a1.z);
        part += w1.w * fast_tanh(x1.w + a1.w);

        #pragma unroll
        for (int off = 32; off > 0; off >>= 1)
            part += __shfl_xor(part, off, 64);

        if (lane == 0) {
            int s = s_base + i;
            int m = mask[(size_t)b * S_SZ + s];
            float sc = fminf(part + ba, 80.f);
            u[(size_t)b * S_SZ + s] = m ? __builtin_expf(sc) : 0.f;
        }
    }
}

// --- Kernel C: partials[b,c,:] = sum_{s in chunk c} u[b,s] * att_feats[b,s,:] ---
// grid (NCHUNK, B), block 256; each thread owns 4 consecutive d (float4)
__global__ __launch_bounds__(256) void k_wsum(const float* __restrict__ feats,
                                              const float* __restrict__ u,
                                              float* __restrict__ partials) {
    int c = blockIdx.x;
    int b = blockIdx.y;
    int t = threadIdx.x;
    __shared__ float w[CHUNK_S];
    int s0 = c * CHUNK_S;
    if (t < CHUNK_S) w[t] = u[(size_t)b * S_SZ + s0 + t];
    __syncthreads();

    const float4* f4 = (const float4*)(feats + ((size_t)b * S_SZ + s0) * RNN);
    float4 acc = {0.f, 0.f, 0.f, 0.f};
    #pragma unroll 4
    for (int i = 0; i < CHUNK_S; ++i) {
        float4 v = f4[(size_t)i * 256 + t];
        float wi = w[i];   // broadcast
        acc.x += wi * v.x;
        acc.y += wi * v.y;
        acc.z += wi * v.z;
        acc.w += wi * v.w;
    }
    float4* out4 = (float4*)partials;
    out4[((size_t)b * NCHUNK + c) * 256 + t] = acc;
}

// --- Kernel D: out[b,:] = (sum_c partials[b,c,:]) / (sum_s u[b,s]) ---
// grid B, block 256
__global__ __launch_bounds__(256) void k_reduce(const float* __restrict__ partials,
                                                const float* __restrict__ u,
                                                float* __restrict__ out) {
    int b = blockIdx.x;
    int t = threadIdx.x;
    __shared__ float red[256];

    float sl = 0.f;
    #pragma unroll
    for (int i = 0; i < S_SZ / 256; ++i)
        sl += u[(size_t)b * S_SZ + t + 256 * i];
    red[t] = sl;
    __syncthreads();
    for (int o = 128; o > 0; o >>= 1) {
        if (t < o) red[t] += red[t + o];
        __syncthreads();
    }
    float inv = 1.f / red[0];

    const float4* p4 = (const float4*)(partials + (size_t)b * NCHUNK * RNN);
    float4 acc = {0.f, 0.f, 0.f, 0.f};
    #pragma unroll
    for (int c = 0; c < NCHUNK; ++c) {
        float4 v = p4[(size_t)c * 256 + t];
        acc.x += v.x;
        acc.y += v.y;
        acc.z += v.z;
        acc.w += v.w;
    }
    acc.x *= inv; acc.y *= inv; acc.z *= inv; acc.w *= inv;
    ((float4*)out)[(size_t)b * 256 + t] = acc;
}

extern "C" void kernel_launch(void* const* d_in, const int* in_sizes, int n_in,
                              void* d_out, int out_size, void* d_ws, size_t ws_size,
                              hipStream_t stream) {
    const float* h         = (const float*)d_in[0];
    const float* att_feats = (const float*)d_in[1];
    const float* p_att     = (const float*)d_in[2];
    const int*   att_masks = (const int*)d_in[3];
    const float* W_h       = (const float*)d_in[4];
    const float* b_h       = (const float*)d_in[5];
    const float* w_a       = (const float*)d_in[6];
    const float* b_a       = (const float*)d_in[7];
    float* out = (float*)d_out;

    float* wsf = (float*)d_ws;
    float* att_h    = wsf + OFF_ATTH;
    float* u        = wsf + OFF_U;
    float* partials = wsf + OFF_PART;

    k_atth<<<dim3(4, B_SZ), 128, 0, stream>>>(h, W_h, b_h, att_h);
    k_scores_u<<<dim3(S_SZ / 32, B_SZ), 256, 0, stream>>>(p_att, att_h, w_a, b_a,
                                                          att_masks, u);
    k_wsum<<<dim3(NCHUNK, B_SZ), 256, 0, stream>>>(att_feats, u, partials);
    k_reduce<<<dim3(B_SZ), 256, 0, stream>>>(partials, u, out);
}

// Round 3
// 179.545 us; speedup vs baseline: 1.0554x; 1.0549x over previous
//
#include <hip/hip_runtime.h>

#define B_SZ 64
#define S_SZ 2048
#define RNN 1024
#define ATT 512
#define NCHUNK 32
#define CHUNK_S (S_SZ / NCHUNK)   // 64

// ws layout in floats:
//   att_h   : [B_SZ*ATT]          off 0        (32768)
//   partials: [B_SZ*NCHUNK*RNN]   off 32768    (2097152)
//   usum    : [B_SZ*NCHUNK]       off 2129920  (2048)
#define OFF_ATTH   0
#define OFF_PART   32768
#define OFF_USUM   2129920

// tanh(x) = 1 - 2/(1 + 2^(x * 2/ln2))
__device__ __forceinline__ float fast_tanh(float x) {
    float t = __builtin_exp2f(x * 2.885390082f);
    return 1.0f - 2.0f * __builtin_amdgcn_rcpf(t + 1.0f);
}

// --- Kernel 0: att_h = h @ W_h^T + b_h   [B,ATT] ---
// grid (4, B), block 128
__global__ __launch_bounds__(128) void k_atth(const float* __restrict__ h,
                                              const float* __restrict__ Wh,
                                              const float* __restrict__ bh,
                                              float* __restrict__ att_h) {
    int b = blockIdx.y;
    int j = blockIdx.x * 128 + threadIdx.x;   // 0..511
    __shared__ float hs[RNN];
    const float* hrow = h + (size_t)b * RNN;
    for (int i = threadIdx.x; i < RNN; i += 128) hs[i] = hrow[i];
    __syncthreads();
    const float4* w4 = (const float4*)(Wh + (size_t)j * RNN);
    const float4* h4 = (const float4*)hs;
    float acc = bh[j];
    #pragma unroll 8
    for (int k = 0; k < RNN / 4; ++k) {
        float4 w = w4[k];
        float4 hv = h4[k];   // wave-uniform index -> LDS broadcast
        acc += w.x * hv.x + w.y * hv.y + w.z * hv.z + w.w * hv.w;
    }
    att_h[(size_t)b * ATT + j] = acc;
}

// --- Fused kernel: per (chunk c, batch b):
//   phase 1: u[s] = mask*exp(w_a . tanh(p[b,s,:]+att_h[b,:]) + b_a)  (s in chunk, LDS only)
//   phase 2: partials[b,c,:] = sum_s u[s]*att_feats[b,s,:];  usum[b,c] = sum_s u[s]
// grid (NCHUNK, B), block 256 = 4 waves; wave handles 16 s-rows in phase 1
__global__ __launch_bounds__(256) void k_fused(const float* __restrict__ p,
                                               const float* __restrict__ att_h,
                                               const float* __restrict__ w_a,
                                               const float* __restrict__ b_a,
                                               const int* __restrict__ mask,
                                               const float* __restrict__ feats,
                                               float* __restrict__ partials,
                                               float* __restrict__ usum) {
    int c = blockIdx.x;
    int b = blockIdx.y;
    int t = threadIdx.x;
    int s0 = c * CHUNK_S;

    __shared__ float ah[ATT];
    __shared__ float wa[ATT];
    __shared__ float mf[CHUNK_S];
    __shared__ float u_lds[CHUNK_S];

    for (int i = t; i < ATT; i += 256) {
        ah[i] = att_h[(size_t)b * ATT + i];
        wa[i] = w_a[i];
    }
    if (t < CHUNK_S) mf[t] = (float)mask[(size_t)b * S_SZ + s0 + t];
    __syncthreads();

    int wave = t >> 6;
    int lane = t & 63;
    float ba = b_a[0];

    const float4* ah4 = (const float4*)ah;
    const float4* wa4 = (const float4*)wa;
    float4 a0 = ah4[lane];
    float4 a1 = ah4[64 + lane];
    float4 w0 = wa4[lane];
    float4 w1 = wa4[64 + lane];

    // phase 1: 16 rows per wave
    const float4* p4 = (const float4*)(p + ((size_t)b * S_SZ + s0 + wave * 16) * ATT);
    #pragma unroll 2
    for (int i = 0; i < 16; ++i) {
        float4 x0 = p4[(size_t)i * 128 + lane];
        float4 x1 = p4[(size_t)i * 128 + 64 + lane];

        float part;
        part  = w0.x * fast_tanh(x0.x + a0.x);
        part += w0.y * fast_tanh(x0.y + a0.y);
        part += w0.z * fast_tanh(x0.z + a0.z);
        part += w0.w * fast_tanh(x0.w + a0.w);
        part += w1.x * fast_tanh(x1.x + a1.x);
        part += w1.y * fast_tanh(x1.y + a1.y);
        part += w1.z * fast_tanh(x1.z + a1.z);
        part += w1.w * fast_tanh(x1.w + a1.w);

        #pragma unroll
        for (int off = 32; off > 0; off >>= 1)
            part += __shfl_xor(part, off, 64);

        if (lane == 0) {
            int sl = wave * 16 + i;
            float sc = fminf(part + ba, 80.f);
            u_lds[sl] = mf[sl] * __builtin_expf(sc);
        }
    }
    __syncthreads();

    // phase 2: weighted row-sum of att_feats chunk; thread t owns cols 4t..4t+3
    const float4* f4 = (const float4*)(feats + ((size_t)b * S_SZ + s0) * RNN);
    float4 acc = {0.f, 0.f, 0.f, 0.f};
    #pragma unroll 4
    for (int i = 0; i < CHUNK_S; ++i) {
        float4 v = f4[(size_t)i * 256 + t];
        float wi = u_lds[i];   // broadcast
        acc.x += wi * v.x;
        acc.y += wi * v.y;
        acc.z += wi * v.z;
        acc.w += wi * v.w;
    }
    ((float4*)partials)[((size_t)b * NCHUNK + c) * 256 + t] = acc;

    if (wave == 0) {
        float s = u_lds[lane];
        #pragma unroll
        for (int off = 32; off > 0; off >>= 1)
            s += __shfl_xor(s, off, 64);
        if (lane == 0) usum[(size_t)b * NCHUNK + c] = s;
    }
}

// --- Reduce: out[b,j] = (sum_c partials[b,c,j]) / (sum_c usum[b,c]) ---
// grid (RNN/256, B), block 256
__global__ __launch_bounds__(256) void k_reduce(const float* __restrict__ partials,
                                                const float* __restrict__ usum,
                                                float* __restrict__ out) {
    int b = blockIdx.y;
    int j = blockIdx.x * 256 + threadIdx.x;

    float tot = 0.f;
    #pragma unroll
    for (int c = 0; c < NCHUNK; ++c)
        tot += usum[(size_t)b * NCHUNK + c];   // block-uniform -> scalar loads

    float acc = 0.f;
    #pragma unroll 8
    for (int c = 0; c < NCHUNK; ++c)
        acc += partials[((size_t)b * NCHUNK + c) * RNN + j];

    out[(size_t)b * RNN + j] = acc / tot;
}

extern "C" void kernel_launch(void* const* d_in, const int* in_sizes, int n_in,
                              void* d_out, int out_size, void* d_ws, size_t ws_size,
                              hipStream_t stream) {
    const float* h         = (const float*)d_in[0];
    const float* att_feats = (const float*)d_in[1];
    const float* p_att     = (const float*)d_in[2];
    const int*   att_masks = (const int*)d_in[3];
    const float* W_h       = (const float*)d_in[4];
    const float* b_h       = (const float*)d_in[5];
    const float* w_a       = (const float*)d_in[6];
    const float* b_a       = (const float*)d_in[7];
    float* out = (float*)d_out;

    float* wsf = (float*)d_ws;
    float* att_h    = wsf + OFF_ATTH;
    float* partials = wsf + OFF_PART;
    float* usum     = wsf + OFF_USUM;

    k_atth<<<dim3(4, B_SZ), 128, 0, stream>>>(h, W_h, b_h, att_h);
    k_fused<<<dim3(NCHUNK, B_SZ), 256, 0, stream>>>(p_att, att_h, w_a, b_a,
                                                    att_masks, att_feats,
                                                    partials, usum);
    k_reduce<<<dim3(RNN / 256, B_SZ), 256, 0, stream>>>(partials, usum, out);
}

// Round 4
// 114.076 us; speedup vs baseline: 1.6611x; 1.5739x over previous
//
#include <hip/hip_runtime.h>

#define B_SZ 64
#define S_SZ 2048
#define RNN 1024
#define ATT 512
#define NCHUNK 32
#define CHUNK_S (S_SZ / NCHUNK)   // 64

// ws layout in floats:
//   att_h   : [B_SZ*ATT]          off 0        (32768)
//   partials: [B_SZ*NCHUNK*RNN]   off 32768    (2097152)
//   usum    : [B_SZ*NCHUNK]       off 2129920  (2048)
#define OFF_ATTH   0
#define OFF_PART   32768
#define OFF_USUM   2129920

// tanh(x) = 1 - 2/(1 + 2^(x * 2/ln2))
__device__ __forceinline__ float fast_tanh(float x) {
    float t = __builtin_exp2f(x * 2.885390082f);
    return 1.0f - 2.0f * __builtin_amdgcn_rcpf(t + 1.0f);
}

// --- Kernel 0: att_h = h @ W_h^T + b_h   [B,ATT] ---
// grid (4, B), block 128
__global__ __launch_bounds__(128) void k_atth(const float* __restrict__ h,
                                              const float* __restrict__ Wh,
                                              const float* __restrict__ bh,
                                              float* __restrict__ att_h) {
    int b = blockIdx.y;
    int j = blockIdx.x * 128 + threadIdx.x;   // 0..511
    __shared__ float hs[RNN];
    const float* hrow = h + (size_t)b * RNN;
    for (int i = threadIdx.x; i < RNN; i += 128) hs[i] = hrow[i];
    __syncthreads();
    const float4* w4 = (const float4*)(Wh + (size_t)j * RNN);
    const float4* h4 = (const float4*)hs;
    float acc = bh[j];
    #pragma unroll 8
    for (int k = 0; k < RNN / 4; ++k) {
        float4 w = w4[k];
        float4 hv = h4[k];   // wave-uniform index -> LDS broadcast
        acc += w.x * hv.x + w.y * hv.y + w.z * hv.z + w.w * hv.w;
    }
    att_h[(size_t)b * ATT + j] = acc;
}

// --- Fused kernel with mask-compaction: per (chunk c, batch b):
//   build compact list of rows with mask!=0 (ballot + rank)
//   phase 1: u_c[k] = exp(w_a . tanh(p[b,row_k,:]+att_h[b,:]) + b_a)  (active rows only)
//   phase 2: partials[b,c,:] = sum_k u_c[k]*att_feats[b,row_k,:];  usum[b,c] = sum u_c
// grid (NCHUNK, B), block 256 = 4 waves
__global__ __launch_bounds__(256) void k_fused(const float* __restrict__ p,
                                               const float* __restrict__ att_h,
                                               const float* __restrict__ w_a,
                                               const float* __restrict__ b_a,
                                               const int* __restrict__ mask,
                                               const float* __restrict__ feats,
                                               float* __restrict__ partials,
                                               float* __restrict__ usum) {
    int c = blockIdx.x;
    int b = blockIdx.y;
    int t = threadIdx.x;
    int s0 = c * CHUNK_S;

    __shared__ float ah[ATT];
    __shared__ float wa[ATT];
    __shared__ float u_c[CHUNK_S];     // compacted unnormalized weights
    __shared__ int   active[CHUNK_S];  // compacted row indices (within chunk)
    __shared__ int   nact_s;

    for (int i = t; i < ATT; i += 256) {
        ah[i] = att_h[(size_t)b * ATT + i];
        wa[i] = w_a[i];
    }
    // wave 0 builds the compacted active-row list
    if (t < CHUNK_S) {
        u_c[t] = 0.f;
        int m = mask[(size_t)b * S_SZ + s0 + t];
        unsigned long long bal = __ballot(m != 0);
        int rank = __popcll(bal & ((1ULL << (unsigned)t) - 1ULL));
        if (m) active[rank] = t;
        if (t == 0) nact_s = (int)__popcll(bal);
    }
    __syncthreads();
    int nact = nact_s;

    int wave = t >> 6;
    int lane = t & 63;
    float ba = b_a[0];

    const float4* ah4 = (const float4*)ah;
    const float4* wa4 = (const float4*)wa;
    float4 a0 = ah4[lane];
    float4 a1 = ah4[64 + lane];
    float4 w0 = wa4[lane];
    float4 w1 = wa4[64 + lane];

    // phase 1: active rows round-robin across 4 waves
    const float4* pbase = (const float4*)(p + ((size_t)b * S_SZ + s0) * ATT);
    for (int k = wave; k < nact; k += 4) {
        int sl = active[k];
        const float4* p4 = pbase + (size_t)sl * 128;
        float4 x0 = p4[lane];
        float4 x1 = p4[64 + lane];

        float part;
        part  = w0.x * fast_tanh(x0.x + a0.x);
        part += w0.y * fast_tanh(x0.y + a0.y);
        part += w0.z * fast_tanh(x0.z + a0.z);
        part += w0.w * fast_tanh(x0.w + a0.w);
        part += w1.x * fast_tanh(x1.x + a1.x);
        part += w1.y * fast_tanh(x1.y + a1.y);
        part += w1.z * fast_tanh(x1.z + a1.z);
        part += w1.w * fast_tanh(x1.w + a1.w);

        #pragma unroll
        for (int off = 32; off > 0; off >>= 1)
            part += __shfl_xor(part, off, 64);

        if (lane == 0) {
            float sc = fminf(part + ba, 80.f);
            u_c[k] = __builtin_expf(sc);   // mask==1 for all active rows
        }
    }
    __syncthreads();

    // phase 2: weighted row-sum over active rows; thread t owns cols 4t..4t+3
    const float4* f4 = (const float4*)(feats + ((size_t)b * S_SZ + s0) * RNN);
    float4 acc = {0.f, 0.f, 0.f, 0.f};
    int k = 0;
    for (; k + 4 <= nact; k += 4) {
        int r0 = active[k + 0], r1 = active[k + 1];
        int r2 = active[k + 2], r3 = active[k + 3];
        float g0 = u_c[k + 0], g1 = u_c[k + 1];
        float g2 = u_c[k + 2], g3 = u_c[k + 3];
        float4 v0 = f4[(size_t)r0 * 256 + t];
        float4 v1 = f4[(size_t)r1 * 256 + t];
        float4 v2 = f4[(size_t)r2 * 256 + t];
        float4 v3 = f4[(size_t)r3 * 256 + t];
        acc.x += g0 * v0.x; acc.y += g0 * v0.y; acc.z += g0 * v0.z; acc.w += g0 * v0.w;
        acc.x += g1 * v1.x; acc.y += g1 * v1.y; acc.z += g1 * v1.z; acc.w += g1 * v1.w;
        acc.x += g2 * v2.x; acc.y += g2 * v2.y; acc.z += g2 * v2.z; acc.w += g2 * v2.w;
        acc.x += g3 * v3.x; acc.y += g3 * v3.y; acc.z += g3 * v3.z; acc.w += g3 * v3.w;
    }
    for (; k < nact; ++k) {
        int r = active[k];
        float g = u_c[k];
        float4 v = f4[(size_t)r * 256 + t];
        acc.x += g * v.x; acc.y += g * v.y; acc.z += g * v.z; acc.w += g * v.w;
    }
    ((float4*)partials)[((size_t)b * NCHUNK + c) * 256 + t] = acc;

    if (wave == 0) {
        float s = u_c[lane];   // zeros beyond nact
        #pragma unroll
        for (int off = 32; off > 0; off >>= 1)
            s += __shfl_xor(s, off, 64);
        if (lane == 0) usum[(size_t)b * NCHUNK + c] = s;
    }
}

// --- Reduce: out[b,j] = (sum_c partials[b,c,j]) / (sum_c usum[b,c]) ---
// grid (RNN/256, B), block 256
__global__ __launch_bounds__(256) void k_reduce(const float* __restrict__ partials,
                                                const float* __restrict__ usum,
                                                float* __restrict__ out) {
    int b = blockIdx.y;
    int j = blockIdx.x * 256 + threadIdx.x;

    float tot = 0.f;
    #pragma unroll
    for (int c = 0; c < NCHUNK; ++c)
        tot += usum[(size_t)b * NCHUNK + c];   // block-uniform -> scalar loads

    float acc = 0.f;
    #pragma unroll 8
    for (int c = 0; c < NCHUNK; ++c)
        acc += partials[((size_t)b * NCHUNK + c) * RNN + j];

    out[(size_t)b * RNN + j] = acc / tot;
}

extern "C" void kernel_launch(void* const* d_in, const int* in_sizes, int n_in,
                              void* d_out, int out_size, void* d_ws, size_t ws_size,
                              hipStream_t stream) {
    const float* h         = (const float*)d_in[0];
    const float* att_feats = (const float*)d_in[1];
    const float* p_att     = (const float*)d_in[2];
    const int*   att_masks = (const int*)d_in[3];
    const float* W_h       = (const float*)d_in[4];
    const float* b_h       = (const float*)d_in[5];
    const float* w_a       = (const float*)d_in[6];
    const float* b_a       = (const float*)d_in[7];
    float* out = (float*)d_out;

    float* wsf = (float*)d_ws;
    float* att_h    = wsf + OFF_ATTH;
    float* partials = wsf + OFF_PART;
    float* usum     = wsf + OFF_USUM;

    k_atth<<<dim3(4, B_SZ), 128, 0, stream>>>(h, W_h, b_h, att_h);
    k_fused<<<dim3(NCHUNK, B_SZ), 256, 0, stream>>>(p_att, att_h, w_a, b_a,
                                                    att_masks, att_feats,
                                                    partials, usum);
    k_reduce<<<dim3(RNN / 256, B_SZ), 256, 0, stream>>>(partials, usum, out);
}